// Round 3
// baseline (184.481 us; speedup 1.0000x reference)
//
#include <hip/hip_runtime.h>
#include <stdint.h>

// Problem constants
#define B_   8
#define S_   2047
#define L_   2048      // S+1 (CLS prepended)
#define H_   256       // HIDDEN
#define NH_  8
#define HD_  32
#define V_   32001     // VOCAB+1
#define CHUNKS_ 8      // k3 t-chunks per batch
#define TCH_ 256       // t per chunk (CHUNKS_*TCH_ == L_)

__device__ __forceinline__ float b2f(unsigned short u) {
    union { uint32_t i; float f; } c; c.i = ((uint32_t)u) << 16; return c.f;
}
__device__ __forceinline__ unsigned short f2b(float f) {
    union { float f; uint32_t i; } c; c.f = f;
    uint32_t x = c.i;
    uint32_t r = (x + 0x7fffu + ((x >> 16) & 1u)) >> 16;
    return (unsigned short)r;
}
__device__ __forceinline__ float sel8(const float a[8], int j) {
    // 8-way select by dynamic index; compiles to cndmask tree (no scratch)
    float v = a[0];
    v = (j == 1) ? a[1] : v;
    v = (j == 2) ? a[2] : v;
    v = (j == 3) ? a[3] : v;
    v = (j == 4) ? a[4] : v;
    v = (j == 5) ? a[5] : v;
    v = (j == 6) ? a[6] : v;
    v = (j == 7) ? a[7] : v;
    return v;
}

// ---------------------------------------------------------------------------
// K0 (grid 8, one block per head n): y0 = emb[2]+pe[0]; q0[k] = wq[n,k,:]·y0;
// qk[n][h] = (sum_k q0[k]*wk[n,k,h]) / sqrt(32)
// ---------------------------------------------------------------------------
__global__ __launch_bounds__(256) void k0_prep(const float* __restrict__ emb,
                                               const float* __restrict__ wq,
                                               const float* __restrict__ wk,
                                               float* __restrict__ qk,
                                               float* __restrict__ y0) {
    __shared__ float y0_l[H_];
    __shared__ float q0p[HD_][8];
    __shared__ float q0_l[HD_];
    int n = blockIdx.x, tid = threadIdx.x;
    float v = emb[2 * H_ + tid] + ((tid & 1) ? 1.0f : 0.0f);  // pe[0]: sin0/cos0
    y0_l[tid] = v;
    if (n == 0) y0[tid] = v;
    __syncthreads();
    {   // q0 partials: thread = (k, part); part covers 32 h
        int k = tid >> 3, part = tid & 7;
        const float* w = wq + (n * HD_ + k) * H_ + part * 32;
        const float* yy = y0_l + part * 32;
        float acc = 0.f;
#pragma unroll
        for (int j = 0; j < 32; ++j) acc += w[j] * yy[j];
        q0p[k][part] = acc;
    }
    __syncthreads();
    if (tid < HD_) {
        float s = 0.f;
#pragma unroll
        for (int j = 0; j < 8; ++j) s += q0p[tid][j];
        q0_l[tid] = s;
    }
    __syncthreads();
    float acc = 0.f;
    for (int k = 0; k < HD_; ++k)
        acc += q0_l[k] * wk[(n * HD_ + k) * H_ + tid];
    qk[n * H_ + tid] = acc * 0.17677669529663687f;  // 1/sqrt(32)
}

// ---------------------------------------------------------------------------
// K1 (grid 512, wave = one t): y[b,t,:] -> ycache (bf16); scores[b,n,t]=qk[n]·y
// Reduction: transpose trick — 27 shuffles per b instead of 48.
// ---------------------------------------------------------------------------
__global__ __launch_bounds__(256) void k1_scores(const int* __restrict__ x,
                                                 const float* __restrict__ emb,
                                                 const float* __restrict__ qkw,
                                                 unsigned short* __restrict__ ycache,
                                                 float* __restrict__ scores) {
    int tid  = threadIdx.x;
    int lane = tid & 63;
    int t    = blockIdx.x * 4 + (tid >> 6);
    int h0   = lane * 4;

    float qr[NH_][4];
#pragma unroll
    for (int n = 0; n < NH_; ++n)
        *(float4*)(&qr[n][0]) = *(const float4*)(qkw + n * H_ + h0);

    const float cdiv = 0.07195578414202881f;  // ln(10000)/128
    float div0 = expf(-(float)(lane * 2) * cdiv);
    float div1 = expf(-(float)(lane * 2 + 1) * cdiv);
    float a0 = (float)t * div0, a1 = (float)t * div1;
    float s0 = sinf(a0), c0 = cosf(a0), s1 = sinf(a1), c1 = cosf(a1);

    int j = lane >> 3;  // head index this lane will own after transpose

    for (int b = 0; b < B_; ++b) {
        int tok = (t == 0) ? 2 : x[b * S_ + t - 1];
        float4 ev = *(const float4*)(emb + tok * H_ + h0);
        float y0v = ev.x + s0;
        float y1v = ev.y + c0;
        float y2v = ev.z + s1;
        float y3v = ev.w + c1;
        ushort4 st;
        st.x = f2b(y0v); st.y = f2b(y1v); st.z = f2b(y2v); st.w = f2b(y3v);
        *(ushort4*)(ycache + ((b * L_ + t) << 8) + h0) = st;

        float acc[NH_];
#pragma unroll
        for (int n = 0; n < NH_; ++n)
            acc[n] = qr[n][0] * y0v + qr[n][1] * y1v + qr[n][2] * y2v + qr[n][3] * y3v;
        // phase A: reduce over xor {32,16,8} -> partials per residue (lane&7)
#pragma unroll
        for (int off = 32; off >= 8; off >>= 1) {
#pragma unroll
            for (int n = 0; n < NH_; ++n)
                acc[n] += __shfl_xor(acc[n], off, 64);
        }
        // phase B: lane picks head j = lane>>3, residue r = lane&7
        float val = sel8(acc, j);
        // phase C: sum the 8 residues (xor {1,2,4} keeps lane>>3 fixed)
#pragma unroll
        for (int off = 1; off <= 4; off <<= 1) val += __shfl_xor(val, off, 64);
        if ((lane & 7) == 0) scores[(b * NH_ + j) * L_ + t] = val;
    }
}

// ---------------------------------------------------------------------------
// K3 (grid 64 = 8b x 8c): softmax WITHOUT max-sub (|s|<1 here) fused with P·y.
// Each wave owns 64 t; writes its own partial (no atomics) + partial exp-sum.
// ---------------------------------------------------------------------------
__global__ __launch_bounds__(256) void k3_pybar(const float* __restrict__ scores,
                                                const unsigned short* __restrict__ ycache,
                                                float* __restrict__ partial,
                                                float* __restrict__ esum_ws) {
    int b = blockIdx.x >> 3, c = blockIdx.x & 7;
    int t0 = c * TCH_;
    int tid = threadIdx.x;
    __shared__ float p_l[NH_][TCH_];

    // phase 1: e = exp(s) into LDS; per-(n) partial sums of e
    {
        int n = tid >> 5, sub = tid & 31;
        const float* sp = scores + (b * NH_ + n) * L_ + t0 + sub;
        float se = 0.f;
#pragma unroll
        for (int jj = 0; jj < 8; ++jj) {
            float e = __expf(sp[jj * 32]);
            p_l[n][sub + jj * 32] = e;
            se += e;
        }
#pragma unroll
        for (int off = 1; off <= 16; off <<= 1) se += __shfl_xor(se, off, 64);
        if (sub == 0) esum_ws[(b * CHUNKS_ + c) * NH_ + n] = se;
    }
    __syncthreads();

    // phase 2: wave w handles t-local [w*64, w*64+64); lane owns 4 h
    int w = tid >> 6, lane = tid & 63;
    float acc[NH_][4] = {};
    const unsigned short* yb = ycache + ((b * L_ + t0 + w * 64) << 8) + lane * 4;
    for (int tt4 = 0; tt4 < 16; ++tt4) {
        float4 p4[NH_];
#pragma unroll
        for (int n = 0; n < NH_; ++n)
            p4[n] = *(const float4*)&p_l[n][w * 64 + tt4 * 4];
#pragma unroll
        for (int q = 0; q < 4; ++q) {
            ushort4 yv = *(const ushort4*)(yb + (tt4 * 4 + q) * H_);
            float y0v = b2f(yv.x), y1v = b2f(yv.y), y2v = b2f(yv.z), y3v = b2f(yv.w);
#pragma unroll
            for (int n = 0; n < NH_; ++n) {
                float p = (q == 0) ? p4[n].x : (q == 1) ? p4[n].y : (q == 2) ? p4[n].z : p4[n].w;
                acc[n][0] += p * y0v;
                acc[n][1] += p * y1v;
                acc[n][2] += p * y2v;
                acc[n][3] += p * y3v;
            }
        }
    }
    float* dst = partial + (size_t)(b * 32 + c * 4 + w) * (NH_ * H_);
#pragma unroll
    for (int n = 0; n < NH_; ++n)
        *(float4*)(dst + n * H_ + lane * 4) = *(float4*)acc[n];
}

// ---------------------------------------------------------------------------
// K4 (grid 8, block per b): reduce partials -> ybar (normalized);
// o = wv·ybar; z = wo·o + 2*y0
// ---------------------------------------------------------------------------
__global__ __launch_bounds__(256) void k4_proj(const float* __restrict__ partial,
                                               const float* __restrict__ esum_ws,
                                               const float* __restrict__ wv,
                                               const float* __restrict__ wo,
                                               const float* __restrict__ y0,
                                               float* __restrict__ z) {
    int b = blockIdx.x, tid = threadIdx.x;
    __shared__ float yb_l[NH_ * H_];
    __shared__ float inv_l[NH_];
    __shared__ float o_l[NH_ * HD_];
    if (tid < NH_) {
        float s = 0.f;
#pragma unroll
        for (int c = 0; c < CHUNKS_; ++c) s += esum_ws[(b * CHUNKS_ + c) * NH_ + tid];
        inv_l[tid] = 1.0f / s;
    }
    __syncthreads();
    for (int n = 0; n < NH_; ++n) {
        const float* pp = partial + (size_t)(b * 32) * (NH_ * H_) + n * H_ + tid;
        float v = 0.f;
#pragma unroll
        for (int w = 0; w < 32; ++w) v += pp[w * (NH_ * H_)];
        yb_l[n * H_ + tid] = v * inv_l[n];
    }
    __syncthreads();
    {   // o[j], j = tid = n*32+k
        int n = tid >> 5;
        const float* w = wv + tid * H_;
        const float* yy = yb_l + n * H_;
        float acc = 0.f;
        for (int h = 0; h < H_; ++h) acc += w[h] * yy[h];
        o_l[tid] = acc;
    }
    __syncthreads();
    {
        const float* w = wo + tid * H_;
        float acc = 0.f;
        for (int jj = 0; jj < NH_ * HD_; ++jj) acc += w[jj] * o_l[jj];
        z[b * H_ + tid] = acc + 2.0f * y0[tid];
    }
}

// ---------------------------------------------------------------------------
// K5 (grid 501): out[b,v] = z[b,:]·wu[v,:]. 16-lane groups own 16-h spans;
// 4 rows per pass per wave -> 8 shuffles/row instead of 48.
// ---------------------------------------------------------------------------
__global__ __launch_bounds__(256) void k5_out(const float* __restrict__ z,
                                              const float* __restrict__ wu,
                                              float* __restrict__ out) {
    int tid = threadIdx.x, lane = tid & 63, w = tid >> 6;
    int m = lane & 15;       // position within 16-lane group -> h-span
    int g = lane >> 4;       // row-in-pass 0..3
    int hb = m * 16;
    float zr[B_][16];
#pragma unroll
    for (int b = 0; b < B_; ++b)
#pragma unroll
        for (int jj = 0; jj < 4; ++jj)
            *(float4*)&zr[b][jj * 4] = *(const float4*)(z + b * H_ + hb + jj * 4);

    __shared__ float o_l[B_ * 65];  // stride 65 breaks bank aliasing
    int base = blockIdx.x * 64;
#pragma unroll
    for (int pass = 0; pass < 4; ++pass) {
        int rl = w * 16 + pass * 4 + g;   // row-local 0..63
        int v = base + rl;
        int vc = (v < V_) ? v : (V_ - 1);
        const float* wr = wu + (size_t)vc * H_ + hb;
        float4 w0 = *(const float4*)(wr);
        float4 w1 = *(const float4*)(wr + 4);
        float4 w2 = *(const float4*)(wr + 8);
        float4 w3 = *(const float4*)(wr + 12);
        float acc[B_];
#pragma unroll
        for (int b = 0; b < B_; ++b) {
            acc[b] = zr[b][0] * w0.x + zr[b][1] * w0.y + zr[b][2] * w0.z + zr[b][3] * w0.w
                   + zr[b][4] * w1.x + zr[b][5] * w1.y + zr[b][6] * w1.z + zr[b][7] * w1.w
                   + zr[b][8] * w2.x + zr[b][9] * w2.y + zr[b][10] * w2.z + zr[b][11] * w2.w
                   + zr[b][12] * w3.x + zr[b][13] * w3.y + zr[b][14] * w3.z + zr[b][15] * w3.w;
        }
#pragma unroll
        for (int off = 1; off <= 8; off <<= 1) {
#pragma unroll
            for (int b = 0; b < B_; ++b) acc[b] += __shfl_xor(acc[b], off, 64);
        }
        if (m < B_) o_l[m * 65 + rl] = sel8(acc, m);
    }
    __syncthreads();
    for (int i = tid; i < B_ * 64; i += 256) {
        int b = i >> 6, vl = i & 63, v = base + vl;
        if (v < V_) out[b * V_ + v] = o_l[b * 65 + vl];
    }
}

// ---------------------------------------------------------------------------
extern "C" void kernel_launch(void* const* d_in, const int* in_sizes, int n_in,
                              void* d_out, int out_size, void* d_ws, size_t ws_size,
                              hipStream_t stream) {
    const int*   x   = (const int*)d_in[0];
    const float* emb = (const float*)d_in[1];
    const float* wq  = (const float*)d_in[2];
    const float* wk  = (const float*)d_in[3];
    const float* wv  = (const float*)d_in[4];
    const float* wo  = (const float*)d_in[5];
    const float* wu  = (const float*)d_in[6];
    float*       out = (float*)d_out;

    // ws layout:
    // qk[2048] | y0[256] | z[2048] | esum[512] | scores[64*2048]
    // | partial[8*32*8*256] | ycache (ushort, 8*2048*256)  ~= 11 MiB total
    float* qk      = (float*)d_ws;
    float* y0      = qk + NH_ * H_;
    float* z       = y0 + H_;
    float* esum    = z + B_ * H_;
    float* scores  = esum + B_ * CHUNKS_ * NH_;
    float* partial = scores + B_ * NH_ * L_;
    unsigned short* ycache = (unsigned short*)(partial + B_ * 32 * NH_ * H_);

    k0_prep  <<<8,   256, 0, stream>>>(emb, wq, wk, qk, y0);
    k1_scores<<<512, 256, 0, stream>>>(x, emb, qk, ycache, scores);
    k3_pybar <<<64,  256, 0, stream>>>(scores, ycache, partial, esum);
    k4_proj  <<<8,   256, 0, stream>>>(partial, esum, wv, wo, y0, z);
    k5_out   <<<(V_ + 63) / 64, 256, 0, stream>>>(z, wu, out);
}

// Round 4
// 165.132 us; speedup vs baseline: 1.1172x; 1.1172x over previous
//
#include <hip/hip_runtime.h>
#include <stdint.h>

// Problem constants
#define B_   8
#define S_   2047
#define L_   2048      // S+1 (CLS prepended)
#define H_   256       // HIDDEN
#define NH_  8
#define HD_  32
#define V_   32001     // VOCAB+1

__device__ __forceinline__ float foldx(float a, int off) {
    return a + __shfl_xor(a, off, 64);
}
__device__ __forceinline__ float sel8(const float a[8], int j) {
    float v = a[0];
    v = (j == 1) ? a[1] : v;
    v = (j == 2) ? a[2] : v;
    v = (j == 3) ? a[3] : v;
    v = (j == 4) ? a[4] : v;
    v = (j == 5) ? a[5] : v;
    v = (j == 6) ? a[6] : v;
    v = (j == 7) ? a[7] : v;
    return v;
}

// ---------------------------------------------------------------------------
// K0 (grid 8, block per head n): y0 = emb[2]+pe[0]; q0[k] = wq[n,k,:]·y0;
// qk[n][h] = (sum_k q0[k]*wk[n,k,h]) / sqrt(32)
// ---------------------------------------------------------------------------
__global__ __launch_bounds__(256) void k0_prep(const float* __restrict__ emb,
                                               const float* __restrict__ wq,
                                               const float* __restrict__ wk,
                                               float* __restrict__ qk,
                                               float* __restrict__ y0) {
    __shared__ float y0_l[H_];
    __shared__ float q0p[HD_][8];
    __shared__ float q0_l[HD_];
    int n = blockIdx.x, tid = threadIdx.x;
    float v = emb[2 * H_ + tid] + ((tid & 1) ? 1.0f : 0.0f);  // pe[0]: sin0/cos0
    y0_l[tid] = v;
    if (n == 0) y0[tid] = v;
    __syncthreads();
    {   // q0 partials: thread = (k, part); part covers 32 h
        int k = tid >> 3, part = tid & 7;
        const float* w = wq + (n * HD_ + k) * H_ + part * 32;
        const float* yy = y0_l + part * 32;
        float acc = 0.f;
#pragma unroll
        for (int j = 0; j < 32; ++j) acc += w[j] * yy[j];
        q0p[k][part] = acc;
    }
    __syncthreads();
    if (tid < HD_) {
        float s = 0.f;
#pragma unroll
        for (int j = 0; j < 8; ++j) s += q0p[tid][j];
        q0_l[tid] = s;
    }
    __syncthreads();
    float acc = 0.f;
    for (int k = 0; k < HD_; ++k)
        acc += q0_l[k] * wk[(n * HD_ + k) * H_ + tid];
    qk[n * H_ + tid] = acc * 0.17677669529663687f;  // 1/sqrt(32)
}

// ---------------------------------------------------------------------------
// K13 fused (grid 256 = b*32+c, 64 t per block, wave owns 16 t):
// y kept in registers; score -> exp -> ybar partial; one LDS block-reduce.
// Softmax has no max-subtraction: |scores| < 1 by construction (w ~ 0.02 N).
// ---------------------------------------------------------------------------
__global__ __launch_bounds__(256, 1) void k13_attn(const int* __restrict__ x,
                                                   const float* __restrict__ emb,
                                                   const float* __restrict__ qkw,
                                                   float* __restrict__ partial,
                                                   float* __restrict__ esum_ws) {
    int bid = blockIdx.x;            // b*32 + c
    int b = bid >> 5, c = bid & 31;
    int tid = threadIdx.x, lane = tid & 63, w = tid >> 6;
    int t0 = c * 64 + w * 16;

    __shared__ float4 p_l4[64][2];               // P[t_local][n] as 2x float4
    __shared__ __align__(16) float red[4][NH_ * H_];  // per-wave ybar partials

    float4 qr[NH_];
#pragma unroll
    for (int n = 0; n < NH_; ++n)
        qr[n] = *(const float4*)(qkw + n * H_ + lane * 4);

    // pe recurrence setup: lane covers h-pairs i0=lane*2, i1=lane*2+1
    const float cdiv = 0.07195578414202881f;     // ln(10000)/128
    float div0 = expf(-(float)(lane * 2) * cdiv);
    float div1 = expf(-(float)(lane * 2 + 1) * cdiv);
    float s0, c0, s1, c1, sd0, cd0, sd1, cd1;
    {
        float a0 = (float)t0 * div0, a1 = (float)t0 * div1;
        s0 = sinf(a0); c0 = cosf(a0); s1 = sinf(a1); c1 = cosf(a1);
        sd0 = sinf(div0); cd0 = cosf(div0);
        sd1 = sinf(div1); cd1 = cosf(div1);
    }

    float4 yreg[16];
    float es = 0.f;

#pragma unroll
    for (int i = 0; i < 16; ++i) {
        int t = t0 + i;
        int tok = (t == 0) ? 2 : x[b * S_ + t - 1];
        float4 ev = *(const float4*)(emb + (size_t)tok * H_ + lane * 4);
        float4 y4;
        y4.x = ev.x + s0; y4.y = ev.y + c0; y4.z = ev.z + s1; y4.w = ev.w + c1;
        yreg[i] = y4;
        // rotate pe by one t-step
        float ns0 = s0 * cd0 + c0 * sd0; c0 = c0 * cd0 - s0 * sd0; s0 = ns0;
        float ns1 = s1 * cd1 + c1 * sd1; c1 = c1 * cd1 - s1 * sd1; s1 = ns1;

        // scores: 8 dots, 17-shuffle fold-reduce (n = lane>>3 after selects)
        float a[NH_];
#pragma unroll
        for (int n = 0; n < NH_; ++n)
            a[n] = qr[n].x * y4.x + qr[n].y * y4.y + qr[n].z * y4.z + qr[n].w * y4.w;
        float m4[4];
#pragma unroll
        for (int k = 0; k < 4; ++k) {
            float lo = foldx(a[k], 32), hi = foldx(a[k + 4], 32);
            m4[k] = (lane & 32) ? hi : lo;
        }
        float m2[2];
#pragma unroll
        for (int k = 0; k < 2; ++k) {
            float lo = foldx(m4[k], 16), hi = foldx(m4[k + 2], 16);
            m2[k] = (lane & 16) ? hi : lo;
        }
        float lo = foldx(m2[0], 8), hi = foldx(m2[1], 8);
        float m1 = (lane & 8) ? hi : lo;
        m1 = foldx(m1, 4); m1 = foldx(m1, 2); m1 = foldx(m1, 1);
        float e = __expf(m1);      // no max-sub: |m1| < 1
        es += e;                   // full row-sum per lane (n = lane>>3)
        if ((lane & 7) == 0)
            ((float*)&p_l4[w * 16 + i][0])[lane >> 3] = e;
    }
    if ((lane & 7) == 0)
        esum_ws[(size_t)(bid * 4 + w) * NH_ + (lane >> 3)] = es;

    // ybar partial over this wave's 16 t (y from registers, P via LDS bcast)
    float4 acc4[NH_];
#pragma unroll
    for (int n = 0; n < NH_; ++n) acc4[n] = make_float4(0.f, 0.f, 0.f, 0.f);
#pragma unroll
    for (int i = 0; i < 16; ++i) {
        float4 pA = p_l4[w * 16 + i][0];
        float4 pB = p_l4[w * 16 + i][1];
        float p[NH_] = {pA.x, pA.y, pA.z, pA.w, pB.x, pB.y, pB.z, pB.w};
        float4 y4 = yreg[i];
#pragma unroll
        for (int n = 0; n < NH_; ++n) {
            acc4[n].x += p[n] * y4.x;
            acc4[n].y += p[n] * y4.y;
            acc4[n].z += p[n] * y4.z;
            acc4[n].w += p[n] * y4.w;
        }
    }
#pragma unroll
    for (int n = 0; n < NH_; ++n)
        *(float4*)&red[w][n * H_ + lane * 4] = acc4[n];
    __syncthreads();
    // cross-wave reduce: thread tid owns 8 consecutive floats
#pragma unroll
    for (int g = 0; g < 2; ++g) {
        int idx = tid * 8 + g * 4;
        float4 r0 = *(const float4*)&red[0][idx];
        float4 r1 = *(const float4*)&red[1][idx];
        float4 r2 = *(const float4*)&red[2][idx];
        float4 r3 = *(const float4*)&red[3][idx];
        float4 s;
        s.x = r0.x + r1.x + r2.x + r3.x;
        s.y = r0.y + r1.y + r2.y + r3.y;
        s.z = r0.z + r1.z + r2.z + r3.z;
        s.w = r0.w + r1.w + r2.w + r3.w;
        *(float4*)(partial + (size_t)bid * (NH_ * H_) + idx) = s;
    }
}

// ---------------------------------------------------------------------------
// K4 (grid 64 = (b,n)): esum reduce -> 1/sum; ybar[b,n,:]; o[b, n*32..+32]
// ---------------------------------------------------------------------------
__global__ __launch_bounds__(256) void k4_heads(const float* __restrict__ partial,
                                                const float* __restrict__ esum_ws,
                                                const float* __restrict__ wv,
                                                float* __restrict__ o_g) {
    int bid = blockIdx.x; int b = bid >> 3, n = bid & 7;
    int tid = threadIdx.x;
    __shared__ float es_l[128];
    __shared__ float inv_s;
    __shared__ float ybar_l[H_];
    __shared__ float op[HD_][8];
    if (tid < 128) es_l[tid] = esum_ws[(size_t)(b * 128 + tid) * NH_ + n];
    __syncthreads();
    if (tid < 64) {
        float v = es_l[tid] + es_l[tid + 64];
#pragma unroll
        for (int off = 32; off > 0; off >>= 1) v += __shfl_xor(v, off, 64);
        if (tid == 0) inv_s = 1.0f / v;
    }
    __syncthreads();
    {
        const float* pp = partial + (size_t)b * 32 * (NH_ * H_) + n * H_ + tid;
        float s = 0.f;
#pragma unroll
        for (int cc = 0; cc < 32; ++cc) s += pp[cc * (NH_ * H_)];
        ybar_l[tid] = s * inv_s;
    }
    __syncthreads();
    {   // o[n*32+k] partial dots: thread = (k, p)
        int k = tid >> 3, p = tid & 7;
        const float* wrow = wv + (size_t)(n * HD_ + k) * H_ + p * 32;
        const float* yy = ybar_l + p * 32;
        float s = 0.f;
#pragma unroll
        for (int j = 0; j < 32; ++j) s += wrow[j] * yy[j];
        op[k][p] = s;
    }
    __syncthreads();
    if (tid < HD_) {
        float s = 0.f;
#pragma unroll
        for (int p = 0; p < 8; ++p) s += op[tid][p];
        o_g[b * (NH_ * HD_) + n * HD_ + tid] = s;
    }
}

// ---------------------------------------------------------------------------
// K4b (grid 8): z[b,i] = wo[i,:]·o[b,:] + 2*y0[i]
// ---------------------------------------------------------------------------
__global__ __launch_bounds__(256) void k4b_z(const float* __restrict__ o_g,
                                             const float* __restrict__ wo,
                                             const float* __restrict__ y0,
                                             float* __restrict__ z) {
    int b = blockIdx.x, tid = threadIdx.x;
    __shared__ float o_l[NH_ * HD_];
    o_l[tid] = o_g[b * (NH_ * HD_) + tid];
    __syncthreads();
    const float* wrow = wo + (size_t)tid * (NH_ * HD_);
    float s = 0.f;
#pragma unroll 8
    for (int j = 0; j < NH_ * HD_; ++j) s += wrow[j] * o_l[j];
    z[b * H_ + tid] = s + 2.0f * y0[tid];
}

// ---------------------------------------------------------------------------
// K5 (grid 501): out[b,v] = z[b,:]·wu[v,:]. 16-lane groups own 16-h spans.
// ---------------------------------------------------------------------------
__global__ __launch_bounds__(256) void k5_out(const float* __restrict__ z,
                                              const float* __restrict__ wu,
                                              float* __restrict__ out) {
    int tid = threadIdx.x, lane = tid & 63, w = tid >> 6;
    int m = lane & 15;
    int g = lane >> 4;
    int hb = m * 16;
    float zr[B_][16];
#pragma unroll
    for (int b = 0; b < B_; ++b)
#pragma unroll
        for (int jj = 0; jj < 4; ++jj)
            *(float4*)&zr[b][jj * 4] = *(const float4*)(z + b * H_ + hb + jj * 4);

    __shared__ float o_l[B_ * 65];
    int base = blockIdx.x * 64;
#pragma unroll
    for (int pass = 0; pass < 4; ++pass) {
        int rl = w * 16 + pass * 4 + g;
        int v = base + rl;
        int vc = (v < V_) ? v : (V_ - 1);
        const float* wr = wu + (size_t)vc * H_ + hb;
        float4 w0 = *(const float4*)(wr);
        float4 w1 = *(const float4*)(wr + 4);
        float4 w2 = *(const float4*)(wr + 8);
        float4 w3 = *(const float4*)(wr + 12);
        float acc[B_];
#pragma unroll
        for (int b = 0; b < B_; ++b) {
            acc[b] = zr[b][0] * w0.x + zr[b][1] * w0.y + zr[b][2] * w0.z + zr[b][3] * w0.w
                   + zr[b][4] * w1.x + zr[b][5] * w1.y + zr[b][6] * w1.z + zr[b][7] * w1.w
                   + zr[b][8] * w2.x + zr[b][9] * w2.y + zr[b][10] * w2.z + zr[b][11] * w2.w
                   + zr[b][12] * w3.x + zr[b][13] * w3.y + zr[b][14] * w3.z + zr[b][15] * w3.w;
        }
#pragma unroll
        for (int off = 1; off <= 8; off <<= 1) {
#pragma unroll
            for (int b = 0; b < B_; ++b) acc[b] += __shfl_xor(acc[b], off, 64);
        }
        if (m < B_) o_l[m * 65 + rl] = sel8(acc, m);
    }
    __syncthreads();
    for (int i = tid; i < B_ * 64; i += 256) {
        int b = i >> 6, vl = i & 63, v = base + vl;
        if (v < V_) out[b * V_ + v] = o_l[b * 65 + vl];
    }
}

// ---------------------------------------------------------------------------
extern "C" void kernel_launch(void* const* d_in, const int* in_sizes, int n_in,
                              void* d_out, int out_size, void* d_ws, size_t ws_size,
                              hipStream_t stream) {
    const int*   x   = (const int*)d_in[0];
    const float* emb = (const float*)d_in[1];
    const float* wq  = (const float*)d_in[2];
    const float* wk  = (const float*)d_in[3];
    const float* wv  = (const float*)d_in[4];
    const float* wo  = (const float*)d_in[5];
    const float* wu  = (const float*)d_in[6];
    float*       out = (float*)d_out;

    // ws layout (floats):
    // qk[2048] | y0[256] | z[2048] | o_g[2048] | esum[8192] | partial[524288]
    // total ~2.2 MiB
    float* qk      = (float*)d_ws;
    float* y0      = qk + NH_ * H_;
    float* z       = y0 + H_;
    float* o_g     = z + B_ * H_;
    float* esum    = o_g + B_ * NH_ * HD_;
    float* partial = esum + 256 * 4 * NH_;

    k0_prep <<<8,   256, 0, stream>>>(emb, wq, wk, qk, y0);
    k13_attn<<<256, 256, 0, stream>>>(x, emb, qk, partial, esum);
    k4_heads<<<64,  256, 0, stream>>>(partial, esum, wv, o_g);
    k4b_z   <<<8,   256, 0, stream>>>(o_g, wo, y0, z);
    k5_out  <<<(V_ + 63) / 64, 256, 0, stream>>>(z, wu, out);
}